// Round 2
// baseline (528.586 us; speedup 1.0000x reference)
//
#include <hip/hip_runtime.h>

// ---------------------------------------------------------------------------
// MultiheadAttention  B=4 S=2048 D=1024 H=16 DK=64
// f32->f16 convert -> 3 proj GEMMs (V writes V^T) -> LDS-free flash attention
// (swapped QK^T, in-register P repack) -> out GEMM.
// ---------------------------------------------------------------------------

typedef _Float16 f16;
typedef _Float16 f16x8 __attribute__((ext_vector_type(8)));
typedef _Float16 f16x4 __attribute__((ext_vector_type(4)));
typedef float f32x4 __attribute__((ext_vector_type(4)));
typedef unsigned int u32;
typedef unsigned int u32x4 __attribute__((ext_vector_type(4)));

#define MFMA16(a, b, c) __builtin_amdgcn_mfma_f32_16x16x32_f16((a), (b), (c), 0, 0, 0)

__device__ __forceinline__ f32x4 vmax4(f32x4 a, f32x4 b) {
  f32x4 r;
  r[0] = fmaxf(a[0], b[0]);
  r[1] = fmaxf(a[1], b[1]);
  r[2] = fmaxf(a[2], b[2]);
  r[3] = fmaxf(a[3], b[3]);
  return r;
}

// ---------------- conversion kernels ----------------
__global__ void cvt_qkv_kernel(const float* __restrict__ q, const float* __restrict__ k,
                               const float* __restrict__ v, f16* __restrict__ qo,
                               f16* __restrict__ ko, f16* __restrict__ vo, int* __restrict__ flags) {
  if (blockIdx.x == 0 && threadIdx.x < 2) flags[threadIdx.x] = 0;  // stream-ordered before mask_flags_kernel
  const int a = blockIdx.x >> 13;
  const long idx = (long)((blockIdx.x & 8191) * 256 + threadIdx.x) * 4;
  const float* src = (a == 0) ? q : (a == 1) ? k : v;
  f16* dst = (a == 0) ? qo : (a == 1) ? ko : vo;
  const float4 f = *reinterpret_cast<const float4*>(src + idx);
  f16x4 o;
  o[0] = (f16)f.x; o[1] = (f16)f.y; o[2] = (f16)f.z; o[3] = (f16)f.w;
  *reinterpret_cast<f16x4*>(dst + idx) = o;
}

__global__ void cvt_w_kernel(const float* __restrict__ w0, const float* __restrict__ w1,
                             const float* __restrict__ w2, const float* __restrict__ w3,
                             f16* __restrict__ o0, f16* __restrict__ o1,
                             f16* __restrict__ o2, f16* __restrict__ o3) {
  const int a = blockIdx.x >> 10;
  const long idx = (long)((blockIdx.x & 1023) * 256 + threadIdx.x) * 4;
  const float* src = (a == 0) ? w0 : (a == 1) ? w1 : (a == 2) ? w2 : w3;
  f16* dst = (a == 0) ? o0 : (a == 1) ? o1 : (a == 2) ? o2 : o3;
  const float4 f = *reinterpret_cast<const float4*>(src + idx);
  f16x4 o;
  o[0] = (f16)f.x; o[1] = (f16)f.y; o[2] = (f16)f.z; o[3] = (f16)f.w;
  *reinterpret_cast<f16x4*>(dst + idx) = o;
}

__global__ void mask_flags_kernel(const unsigned char* __restrict__ am,
                                  const unsigned char* __restrict__ kp, int* __restrict__ flags) {
  const int tid = blockIdx.x * 256 + threadIdx.x;
  const uint4 u = reinterpret_cast<const uint4*>(am)[tid];
  if (u.x | u.y | u.z | u.w) atomicOr(flags, 1);
  if (tid < 512) {
    const uint4 w = reinterpret_cast<const uint4*>(kp)[tid];
    if (w.x | w.y | w.z | w.w) atomicOr(flags + 1, 1);
  }
}

// ---------------- GEMM: C[M,N] = A[M,K] * B[N,K]^T + bias[N] ----------------
// 128x128 tile, 4 waves each 64x64 (4x4 of 16x16x32), BK=64, swizzled LDS.
// TRANSP: write C^T into [4096][2048] f16 layout idx = (b*1024 + col)*2048 + s
// (b = row>>11, s = row&2047) -- used for V so attention reads V^T rows.
__device__ __forceinline__ void stC(float* p, float v) { *p = v; }
__device__ __forceinline__ void stC(f16* p, float v) { *p = (f16)v; }

template <typename OutT, bool TRANSP>
__global__ __launch_bounds__(256) void gemm_bt(const f16* __restrict__ A, const f16* __restrict__ B,
                                               const float* __restrict__ bias, OutT* __restrict__ C,
                                               int M, int N, int K) {
  __shared__ __align__(16) char As[16384];
  __shared__ __align__(16) char Bs[16384];
  const int tid = threadIdx.x;
  const int w = tid >> 6, lane = tid & 63, t = lane & 15, g = lane >> 4;
  const int nb = N >> 7;
  const int br = blockIdx.x / nb, bc = blockIdx.x - br * nb;
  const int rowBase = br << 7, colBase = bc << 7;
  const int wr = w >> 1, wc = w & 1;

  f32x4 acc[4][4];
#pragma unroll
  for (int m = 0; m < 4; ++m)
#pragma unroll
    for (int n = 0; n < 4; ++n) acc[m][n] = (f32x4){0.f, 0.f, 0.f, 0.f};

  const int nk = K >> 6;
  for (int ks = 0; ks < nk; ++ks) {
    const int k0 = ks << 6;
    f16x8 va[4], vb[4];
#pragma unroll
    for (int c = 0; c < 4; ++c) {
      const int li = (c * 4 + w) * 64 + lane;
      const int row = li >> 3;
      const int colb = (li & 7) << 4;
      va[c] = *reinterpret_cast<const f16x8*>(A + (size_t)(rowBase + row) * K + k0 + (colb >> 1));
      vb[c] = *reinterpret_cast<const f16x8*>(B + (size_t)(colBase + row) * K + k0 + (colb >> 1));
    }
    __syncthreads();
#pragma unroll
    for (int c = 0; c < 4; ++c) {
      const int li = (c * 4 + w) * 64 + lane;
      const int row = li >> 3;
      const int colb = (li & 7) << 4;
      const int sw = colb ^ ((row & 7) << 4);
      *reinterpret_cast<f16x8*>(As + row * 128 + sw) = va[c];
      *reinterpret_cast<f16x8*>(Bs + row * 128 + sw) = vb[c];
    }
    __syncthreads();
#pragma unroll
    for (int kk = 0; kk < 2; ++kk) {
      f16x8 af[4], bf[4];
#pragma unroll
      for (int m = 0; m < 4; ++m) {
        const int row = (wr << 6) + (m << 4) + t;
        af[m] = *reinterpret_cast<const f16x8*>(As + row * 128 + (((kk << 6) + (g << 4)) ^ ((row & 7) << 4)));
      }
#pragma unroll
      for (int n = 0; n < 4; ++n) {
        const int row = (wc << 6) + (n << 4) + t;
        bf[n] = *reinterpret_cast<const f16x8*>(Bs + row * 128 + (((kk << 6) + (g << 4)) ^ ((row & 7) << 4)));
      }
#pragma unroll
      for (int m = 0; m < 4; ++m)
#pragma unroll
        for (int n = 0; n < 4; ++n) acc[m][n] = MFMA16(af[m], bf[n], acc[m][n]);
    }
  }
  // epilogue. D frag: col = lane&15, row = (lane>>4)*4 + r (m89-verified).
#pragma unroll
  for (int n = 0; n < 4; ++n) {
    const int col = colBase + (wc << 6) + (n << 4) + t;
    const float bv = bias[col];
#pragma unroll
    for (int m = 0; m < 4; ++m) {
      const int row0 = rowBase + (wr << 6) + (m << 4) + (g << 2);
      if (TRANSP) {
        const int bI = row0 >> 11, s0 = row0 & 2047;
        f16x4 vv;
#pragma unroll
        for (int r = 0; r < 4; ++r) vv[r] = (f16)(acc[m][n][r] + bv);
        *reinterpret_cast<f16x4*>((f16*)C + ((size_t)(bI << 10) + col) * 2048 + s0) = vv;
      } else {
#pragma unroll
        for (int r = 0; r < 4; ++r) stC(C + (size_t)(row0 + r) * N + col, acc[m][n][r] + bv);
      }
    }
  }
}

// ---------------- flash attention (LDS-free, swapped QK^T) ----------------
// Per block: 4 independent waves, each owns 32 q-rows (2 strips of 16). KVBLK=64.
// S^T = mfma(K, Q): lane (t,g) holds S^T[kv=kv0+kvt*16+4g+r][q=q0+s*16+t].
// Softmax per q is a 4-lane-column reduce (xor 16, 32).
// P repacked in-register (cvt_pkrtz + shfl) into the PV B-fragment.
// PV computes O^T = mfma(V^T, P^T); V^T fragments are 16B global loads from vT.
__global__ __launch_bounds__(256) void attn_kernel(const f16* __restrict__ qh, const f16* __restrict__ kh,
                                                   const f16* __restrict__ vT,
                                                   const unsigned char* __restrict__ am,
                                                   const unsigned char* __restrict__ kp,
                                                   const int* __restrict__ flags, f16* __restrict__ y) {
  const int tid = threadIdx.x;
  const int w = tid >> 6, lane = tid & 63, t = lane & 15, g = lane >> 4;
  const int qt = blockIdx.x & 15, bh = blockIdx.x >> 4;
  const int h = bh & 15, b = bh >> 4;
  const int hc = h << 6;
  const int q0 = qt * 128 + w * 32;
  const size_t rowQ = (size_t)b * 2048 + q0;
  const size_t kBase = (size_t)b * 2048 * 1024 + hc;      // + kv*1024 + dkoff
  const size_t vBase = (size_t)bh * 64 * 2048;            // + (dk)*2048 + kv

  // Q B-fragments, scale 1/sqrt(64)=0.125 folded in (exact in f16).
  f16x8 bq[2][2];
#pragma unroll
  for (int s = 0; s < 2; ++s)
#pragma unroll
    for (int h2 = 0; h2 < 2; ++h2) {
      f16x8 qv = *reinterpret_cast<const f16x8*>(qh + (rowQ + s * 16 + t) * 1024 + hc + h2 * 32 + g * 8);
#pragma unroll
      for (int j = 0; j < 8; ++j) qv[j] = qv[j] * (f16)0.125f;
      bq[s][h2] = qv;
    }

  f32x4 o[2][4];
#pragma unroll
  for (int s = 0; s < 2; ++s)
#pragma unroll
    for (int d = 0; d < 4; ++d) o[s][d] = (f32x4){0.f, 0.f, 0.f, 0.f};
  float mx[2] = {-3.0e38f, -3.0e38f};
  float lsum[2] = {0.f, 0.f};
  const int f0 = flags[0], f1 = flags[1];

  const int srcA = ((((g << 1) + 0) & 3) << 4) | t;
  const int srcB = ((((g << 1) + 1) & 3) << 4) | t;
  const bool glow = (g < 2);

  for (int tk = 0; tk < 32; ++tk) {
    const int kv0 = tk << 6;
    // K A-fragments: row kv = kv0 + kvt*16 + t, k = dk h2*32 + g*8..+8
    f16x8 ak[4][2];
#pragma unroll
    for (int kvt = 0; kvt < 4; ++kvt)
#pragma unroll
      for (int h2 = 0; h2 < 2; ++h2)
        ak[kvt][h2] = *reinterpret_cast<const f16x8*>(kh + kBase + (size_t)(kv0 + kvt * 16 + t) * 1024 + h2 * 32 + g * 8);
    // V^T A-fragments: row dk = dkt*16 + t, k = kv kk*32 + g*8..+8
    f16x8 av[4][2];
#pragma unroll
    for (int dkt = 0; dkt < 4; ++dkt)
#pragma unroll
      for (int kk = 0; kk < 2; ++kk)
        av[dkt][kk] = *reinterpret_cast<const f16x8*>(vT + vBase + (size_t)(dkt * 16 + t) * 2048 + kv0 + kk * 32 + g * 8);

    f16x8 pb[2][2];
#pragma unroll
    for (int s = 0; s < 2; ++s) {
      // QK^T (swapped): S^T tile per kvt
      f32x4 sT[4];
#pragma unroll
      for (int kvt = 0; kvt < 4; ++kvt) {
        f32x4 z = (f32x4){0.f, 0.f, 0.f, 0.f};
        z = MFMA16(ak[kvt][0], bq[s][0], z);
        z = MFMA16(ak[kvt][1], bq[s][1], z);
        sT[kvt] = z;
      }
      if (f0 | f1) {  // mask slow path (skipped for all-false masks; wave-uniform)
        const int qq = q0 + s * 16 + t;
        for (int kvt = 0; kvt < 4; ++kvt)
          for (int r = 0; r < 4; ++r) {
            const int kv = kv0 + kvt * 16 + (g << 2) + r;
            if ((f1 && kp[(size_t)b * 2048 + kv]) || (f0 && am[(size_t)qq * 2048 + kv])) sT[kvt][r] = -1e9f;
          }
      }
      // online softmax for this strip's q = q0 + s*16 + t (column reduce over g)
      f32x4 m4 = vmax4(vmax4(sT[0], sT[1]), vmax4(sT[2], sT[3]));
      float tm = fmaxf(fmaxf(m4[0], m4[1]), fmaxf(m4[2], m4[3]));
      tm = fmaxf(tm, __shfl_xor(tm, 16));
      tm = fmaxf(tm, __shfl_xor(tm, 32));
      const float nm = fmaxf(mx[s], tm);
      const float al = __expf(mx[s] - nm);
      mx[s] = nm;
      f32x4 ps4 = (f32x4){0.f, 0.f, 0.f, 0.f};
      u32 pk[8];
#pragma unroll
      for (int kvt = 0; kvt < 4; ++kvt) {
        f32x4 p;
#pragma unroll
        for (int r = 0; r < 4; ++r) p[r] = __expf(sT[kvt][r] - nm);
        ps4 += p;
        pk[kvt * 2 + 0] = __builtin_bit_cast(u32, __builtin_amdgcn_cvt_pkrtz(p[0], p[1]));
        pk[kvt * 2 + 1] = __builtin_bit_cast(u32, __builtin_amdgcn_cvt_pkrtz(p[2], p[3]));
      }
      lsum[s] = lsum[s] * al + (ps4[0] + ps4[1] + ps4[2] + ps4[3]);
      // repack P^T into B-fragment: target lane (t,g) elem e needs kv=32kk+8g+e.
      u32 tA[8], tB[8];
#pragma unroll
      for (int i = 0; i < 8; ++i) {
        tA[i] = (u32)__shfl((int)pk[i], srcA, 64);
        tB[i] = (u32)__shfl((int)pk[i], srcB, 64);
      }
#pragma unroll
      for (int kk = 0; kk < 2; ++kk) {
        u32x4 wv;
        wv[0] = glow ? tA[4 * kk + 0] : tA[4 * kk + 2];
        wv[1] = glow ? tA[4 * kk + 1] : tA[4 * kk + 3];
        wv[2] = glow ? tB[4 * kk + 0] : tB[4 * kk + 2];
        wv[3] = glow ? tB[4 * kk + 1] : tB[4 * kk + 3];
        pb[s][kk] = __builtin_bit_cast(f16x8, wv);
      }
      // rescale O^T
#pragma unroll
      for (int dkt = 0; dkt < 4; ++dkt) o[s][dkt] *= al;
    }
    // PV: O^T[dk][q] += V^T x P^T
#pragma unroll
    for (int s = 0; s < 2; ++s)
#pragma unroll
      for (int dkt = 0; dkt < 4; ++dkt) {
        o[s][dkt] = MFMA16(av[dkt][0], pb[s][0], o[s][dkt]);
        o[s][dkt] = MFMA16(av[dkt][1], pb[s][1], o[s][dkt]);
      }
  }
  // finalize: row sum over the 4-lane column, normalize, store.
#pragma unroll
  for (int s = 0; s < 2; ++s) {
    float l = lsum[s];
    l += __shfl_xor(l, 16);
    l += __shfl_xor(l, 32);
    const float inv = 1.0f / l;
#pragma unroll
    for (int dkt = 0; dkt < 4; ++dkt) {
      f16x4 vv;
#pragma unroll
      for (int r = 0; r < 4; ++r) vv[r] = (f16)(o[s][dkt][r] * inv);
      *reinterpret_cast<f16x4*>(y + (rowQ + s * 16 + t) * 1024 + hc + dkt * 16 + (g << 2)) = vv;
    }
  }
}

// ---------------- launch ----------------
extern "C" void kernel_launch(void* const* d_in, const int* in_sizes, int n_in,
                              void* d_out, int out_size, void* d_ws, size_t ws_size,
                              hipStream_t stream) {
  const float* q = (const float*)d_in[0];
  const float* k = (const float*)d_in[1];
  const float* v = (const float*)d_in[2];
  const unsigned char* kpm = (const unsigned char*)d_in[3];
  const unsigned char* amask = (const unsigned char*)d_in[4];
  const float* Wq = (const float*)d_in[5];
  const float* bq = (const float*)d_in[6];
  const float* Wk = (const float*)d_in[7];
  const float* bk = (const float*)d_in[8];
  const float* Wv = (const float*)d_in[9];
  const float* bv = (const float*)d_in[10];
  const float* Wo = (const float*)d_in[11];
  const float* bo = (const float*)d_in[12];
  float* out = (float*)d_out;

  char* ws = (char*)d_ws;
  const size_t SZ = 16777216;  // bytes of one [8192,1024] f16 buffer
  f16* qb = (f16*)(ws + 0 * SZ);
  f16* kb = (f16*)(ws + 1 * SZ);
  f16* vb = (f16*)(ws + 2 * SZ);
  f16* qhp = (f16*)(ws + 3 * SZ);
  f16* khp = (f16*)(ws + 4 * SZ);
  f16* vhT = (f16*)(ws + 5 * SZ);  // [4096][2048] f16: (b*1024 + h*64 + dk) x kv
  f16* yb = (f16*)(ws + 6 * SZ);
  f16* wqb = (f16*)(ws + 7 * SZ + 0 * 2097152);
  f16* wkb = (f16*)(ws + 7 * SZ + 1 * 2097152);
  f16* wvb = (f16*)(ws + 7 * SZ + 2 * 2097152);
  f16* wob = (f16*)(ws + 7 * SZ + 3 * 2097152);
  int* flags = (int*)(ws + 7 * SZ + 4 * 2097152);

  cvt_qkv_kernel<<<24576, 256, 0, stream>>>(q, k, v, qb, kb, vb, flags);
  cvt_w_kernel<<<4096, 256, 0, stream>>>(Wq, Wk, Wv, Wo, wqb, wkb, wvb, wob);
  mask_flags_kernel<<<1024, 256, 0, stream>>>(amask, kpm, flags);
  gemm_bt<f16, false><<<512, 256, 0, stream>>>(qb, wqb, bq, qhp, 8192, 1024, 1024);
  gemm_bt<f16, false><<<512, 256, 0, stream>>>(kb, wkb, bk, khp, 8192, 1024, 1024);
  gemm_bt<f16, true><<<512, 256, 0, stream>>>(vb, wvb, bv, vhT, 8192, 1024, 1024);
  attn_kernel<<<1024, 256, 0, stream>>>(qhp, khp, vhT, amask, kpm, flags, yb);
  gemm_bt<float, false><<<512, 256, 0, stream>>>(yb, wob, bo, out, 8192, 1024, 1024);
}

// Round 3
// 501.361 us; speedup vs baseline: 1.0543x; 1.0543x over previous
//
#include <hip/hip_runtime.h>

// ---------------------------------------------------------------------------
// MultiheadAttention  B=4 S=2048 D=1024 H=16 DK=64
// cvt -> merged QKV proj GEMM (m97-style global_load_lds, V writes V^T)
//     -> flash attention (swapped QK^T, P^T via per-wave swizzled LDS)
//     -> out GEMM.
// ---------------------------------------------------------------------------

typedef _Float16 f16;
typedef _Float16 f16x8 __attribute__((ext_vector_type(8)));
typedef _Float16 f16x4 __attribute__((ext_vector_type(4)));
typedef float f32x4 __attribute__((ext_vector_type(4)));
typedef unsigned int u32;
typedef unsigned int u32x2 __attribute__((ext_vector_type(2)));

#define MFMA16(a, b, c) __builtin_amdgcn_mfma_f32_16x16x32_f16((a), (b), (c), 0, 0, 0)

__device__ __forceinline__ f32x4 vmax4(f32x4 a, f32x4 b) {
  f32x4 r;
  r[0] = fmaxf(a[0], b[0]);
  r[1] = fmaxf(a[1], b[1]);
  r[2] = fmaxf(a[2], b[2]);
  r[3] = fmaxf(a[3], b[3]);
  return r;
}

// async global->LDS, 16B per lane; LDS dest = wave-uniform base + lane*16.
__device__ __forceinline__ void gload16(const f16* gp, char* lp) {
  __builtin_amdgcn_global_load_lds((__attribute__((address_space(1))) void*)(void*)gp,
                                   (__attribute__((address_space(3))) void*)lp, 16, 0, 0);
}

// bijective XCD swizzle (nblk % 8 == 0): same-XCD blocks get contiguous work.
__device__ __forceinline__ int xcd_swz(int bid, int nblk) {
  return (bid & 7) * (nblk >> 3) + (bid >> 3);
}

// ---------------- conversion kernels ----------------
// blocks [0,24576): q,k,v (8192 blocks each); [24576,28672): Wq,Wk,Wv,Wo (1024 each).
__global__ void cvt_all(const float* __restrict__ q, const float* __restrict__ k,
                        const float* __restrict__ v, const float* __restrict__ w0,
                        const float* __restrict__ w1, const float* __restrict__ w2,
                        const float* __restrict__ w3, f16* __restrict__ qo,
                        f16* __restrict__ ko, f16* __restrict__ vo, f16* __restrict__ o0,
                        f16* __restrict__ o1, f16* __restrict__ o2, f16* __restrict__ o3,
                        int* __restrict__ flags) {
  const int bid = blockIdx.x;
  if (bid == 0 && threadIdx.x < 2) flags[threadIdx.x] = 0;  // stream-ordered before mask_flags
  const float* src;
  f16* dst;
  long idx;
  if (bid < 24576) {
    const int a = bid >> 13;
    idx = (long)(((bid & 8191) << 8) + threadIdx.x) * 4;
    src = (a == 0) ? q : (a == 1) ? k : v;
    dst = (a == 0) ? qo : (a == 1) ? ko : vo;
  } else {
    const int wb = bid - 24576;
    const int a = wb >> 10;
    idx = (long)(((wb & 1023) << 8) + threadIdx.x) * 4;
    src = (a == 0) ? w0 : (a == 1) ? w1 : (a == 2) ? w2 : w3;
    dst = (a == 0) ? o0 : (a == 1) ? o1 : (a == 2) ? o2 : o3;
  }
  const float4 f = *reinterpret_cast<const float4*>(src + idx);
  f16x4 o;
  o[0] = (f16)f.x; o[1] = (f16)f.y; o[2] = (f16)f.z; o[3] = (f16)f.w;
  *reinterpret_cast<f16x4*>(dst + idx) = o;
}

__global__ void mask_flags_kernel(const unsigned char* __restrict__ am,
                                  const unsigned char* __restrict__ kp, int* __restrict__ flags) {
  const int tid = blockIdx.x * 256 + threadIdx.x;
  const uint4 u = reinterpret_cast<const uint4*>(am)[tid];
  if (u.x | u.y | u.z | u.w) atomicOr(flags, 1);
  if (tid < 512) {
    const uint4 w = reinterpret_cast<const uint4*>(kp)[tid];
    if (w.x | w.y | w.z | w.w) atomicOr(flags + 1, 1);
  }
}

// ---------------- GEMM core: C[M,1024] = A[M,1024] * B[1024,1024]^T + bias ----
// m97 structure: 128x128 tile, BK=64, global_load_lds(16B) -> LINEAR LDS,
// 2 barriers per K-step, 4 waves x (64x64 out), 16x16x32 MFMA.
__device__ __forceinline__ void stC(float* p, float v) { *p = v; }
__device__ __forceinline__ void stC(f16* p, float v) { *p = (f16)v; }

template <typename OutT>
__device__ __forceinline__ void gemm_core(const f16* __restrict__ A, const f16* __restrict__ B,
                                          const float* __restrict__ bias, OutT* __restrict__ C,
                                          int br, int bc, int transp) {
  __shared__ __align__(16) char As[16384];  // [128 rows][64 k] f16, linear
  __shared__ __align__(16) char Bs[16384];
  const int tid = threadIdx.x;
  const int w = tid >> 6, lane = tid & 63, t = lane & 15, g = lane >> 4;
  const int rowBase = br << 7, colBase = bc << 7;
  const int wr = w >> 1, wc = w & 1;
  const int lr = lane >> 3, lc = lane & 7;  // lane's (row, 16B-col) within an 8-row chunk

  f32x4 acc[4][4];
#pragma unroll
  for (int m = 0; m < 4; ++m)
#pragma unroll
    for (int n = 0; n < 4; ++n) acc[m][n] = (f32x4){0.f, 0.f, 0.f, 0.f};

  const f16* gA = A + (size_t)(rowBase + w * 32 + lr) * 1024 + lc * 8;
  const f16* gB = B + (size_t)(colBase + w * 32 + lr) * 1024 + lc * 8;
  char* lA = As + w * 32 * 128;
  char* lB = Bs + w * 32 * 128;

  for (int ks = 0; ks < 16; ++ks) {
    const int k0 = ks << 6;
#pragma unroll
    for (int c = 0; c < 4; ++c) {
      gload16(gA + (size_t)(c * 8) * 1024 + k0, lA + c * 1024);
      gload16(gB + (size_t)(c * 8) * 1024 + k0, lB + c * 1024);
    }
    __syncthreads();  // drains vmcnt: staged tile visible
#pragma unroll
    for (int kk = 0; kk < 2; ++kk) {
      f16x8 af[4], bf[4];
#pragma unroll
      for (int m = 0; m < 4; ++m)
        af[m] = *reinterpret_cast<const f16x8*>(As + ((wr << 6) + (m << 4) + t) * 128 + (kk << 6) + (g << 4));
#pragma unroll
      for (int n = 0; n < 4; ++n)
        bf[n] = *reinterpret_cast<const f16x8*>(Bs + ((wc << 6) + (n << 4) + t) * 128 + (kk << 6) + (g << 4));
#pragma unroll
      for (int m = 0; m < 4; ++m)
#pragma unroll
        for (int n = 0; n < 4; ++n) acc[m][n] = MFMA16(af[m], bf[n], acc[m][n]);
    }
    __syncthreads();  // readers done before next tile's gload_lds overwrites
  }
  // epilogue. D frag: col = lane&15, row = (lane>>4)*4 + r (m89-verified).
#pragma unroll
  for (int n = 0; n < 4; ++n) {
    const int col = colBase + (wc << 6) + (n << 4) + t;
    const float bv = bias[col];
#pragma unroll
    for (int m = 0; m < 4; ++m) {
      const int row0 = rowBase + (wr << 6) + (m << 4) + (g << 2);
      if (transp) {  // write C^T: [4096][2048] f16, idx = (b*1024 + col)*2048 + s
        const int bI = row0 >> 11, s0 = row0 & 2047;
        f16x4 vv;
#pragma unroll
        for (int r = 0; r < 4; ++r) vv[r] = (f16)(acc[m][n][r] + bv);
        *reinterpret_cast<f16x4*>((f16*)C + ((size_t)(bI << 10) + col) * 2048 + s0) = vv;
      } else {
#pragma unroll
        for (int r = 0; r < 4; ++r) stC(C + (size_t)(row0 + r) * 1024 + col, acc[m][n][r] + bv);
      }
    }
  }
}

// merged Q/K/V projections: 1536 blocks (512 per GEMM), XCD-swizzled.
__global__ __launch_bounds__(256) void gemm_qkv(const f16* __restrict__ qb, const f16* __restrict__ kb,
                                                const f16* __restrict__ vb, const f16* __restrict__ wq,
                                                const f16* __restrict__ wk, const f16* __restrict__ wv,
                                                const float* __restrict__ bq, const float* __restrict__ bk,
                                                const float* __restrict__ bv, f16* __restrict__ qo,
                                                f16* __restrict__ ko, f16* __restrict__ vT) {
  const int lid = xcd_swz(blockIdx.x, 1536);
  const int bz = lid >> 9, rem = lid & 511;
  const int br = rem >> 3, bc = rem & 7;
  const f16* A = (bz == 0) ? qb : (bz == 1) ? kb : vb;
  const f16* Bm = (bz == 0) ? wq : (bz == 1) ? wk : wv;
  const float* bias = (bz == 0) ? bq : (bz == 1) ? bk : bv;
  f16* C = (bz == 0) ? qo : (bz == 1) ? ko : vT;
  gemm_core<f16>(A, Bm, bias, C, br, bc, bz == 2);
}

__global__ __launch_bounds__(256) void gemm_out(const f16* __restrict__ A, const f16* __restrict__ Bm,
                                                const float* __restrict__ bias, float* __restrict__ C) {
  const int lid = xcd_swz(blockIdx.x, 512);
  gemm_core<float>(A, Bm, bias, C, lid >> 3, lid & 7, 0);
}

// ---------------- flash attention (swapped QK^T, P^T via per-wave LDS) -------
// 4 independent waves/block, 32 q-rows each (2 strips of 16). KVBLK=64.
// S^T = mfma(K, Q): lane (t,g) holds S^T[kv=kv0+kvt*16+4g+r][q=q0+s*16+t].
// P^T round-trips a per-wave XOR-swizzled LDS tile [q=16 rows][kv=64 cols]:
//   4x ds_write_b64 + 2x ds_read_b128 per strip (replaces 16 ds_bpermute).
// PV: O^T = mfma(V^T, P^T); V^T fragments are 16B global loads.
__global__ __launch_bounds__(256) void attn_kernel(const f16* __restrict__ qh, const f16* __restrict__ kh,
                                                   const f16* __restrict__ vT,
                                                   const unsigned char* __restrict__ am,
                                                   const unsigned char* __restrict__ kp,
                                                   const int* __restrict__ flags, f16* __restrict__ y) {
  __shared__ __align__(16) char PB[16384];  // 4 waves x (2 strips x [16 q][64 kv] f16)
  const int tid = threadIdx.x;
  const int w = tid >> 6, lane = tid & 63, t = lane & 15, g = lane >> 4;
  const int lid = xcd_swz(blockIdx.x, 1024);  // each head's 16 q-tiles share an XCD L2
  const int qt = lid & 15, bh = lid >> 4;
  const int h = bh & 15, b = bh >> 4;
  const int hc = h << 6;
  const int q0 = qt * 128 + w * 32;
  const size_t rowQ = (size_t)b * 2048 + q0;
  const size_t kBase = (size_t)b * 2048 * 1024 + hc;
  const size_t vBase = (size_t)bh * 64 * 2048;
  char* PBw = PB + (w << 12);

  // Q B-fragments, scale 1/8 folded in (exact in f16).
  f16x8 bq[2][2];
#pragma unroll
  for (int s = 0; s < 2; ++s)
#pragma unroll
    for (int h2 = 0; h2 < 2; ++h2) {
      f16x8 qv = *reinterpret_cast<const f16x8*>(qh + (rowQ + s * 16 + t) * 1024 + hc + h2 * 32 + g * 8);
#pragma unroll
      for (int j = 0; j < 8; ++j) qv[j] = qv[j] * (f16)0.125f;
      bq[s][h2] = qv;
    }

  f32x4 o[2][4];
#pragma unroll
  for (int s = 0; s < 2; ++s)
#pragma unroll
    for (int d = 0; d < 4; ++d) o[s][d] = (f32x4){0.f, 0.f, 0.f, 0.f};
  float mx[2] = {-3.0e38f, -3.0e38f};
  float lsum[2] = {0.f, 0.f};
  const int f0 = flags[0], f1 = flags[1];
  const int swz = (t & 7) << 4;

  for (int tk = 0; tk < 32; ++tk) {
    const int kv0 = tk << 6;
    f16x8 ak[4][2];
#pragma unroll
    for (int kvt = 0; kvt < 4; ++kvt)
#pragma unroll
      for (int h2 = 0; h2 < 2; ++h2)
        ak[kvt][h2] = *reinterpret_cast<const f16x8*>(kh + kBase + (size_t)(kv0 + kvt * 16 + t) * 1024 + h2 * 32 + g * 8);
    f16x8 av[4][2];
#pragma unroll
    for (int dkt = 0; dkt < 4; ++dkt)
#pragma unroll
      for (int kk = 0; kk < 2; ++kk)
        av[dkt][kk] = *reinterpret_cast<const f16x8*>(vT + vBase + (size_t)(dkt * 16 + t) * 2048 + kv0 + kk * 32 + g * 8);

    f16x8 pb[2][2];
#pragma unroll
    for (int s = 0; s < 2; ++s) {
      char* PBs = PBw + (s << 11);
      f32x4 sT[4];
      __builtin_amdgcn_s_setprio(1);
#pragma unroll
      for (int kvt = 0; kvt < 4; ++kvt) {
        f32x4 z = (f32x4){0.f, 0.f, 0.f, 0.f};
        z = MFMA16(ak[kvt][0], bq[s][0], z);
        z = MFMA16(ak[kvt][1], bq[s][1], z);
        sT[kvt] = z;
      }
      __builtin_amdgcn_s_setprio(0);
      if (f0 | f1) {  // mask slow path (wave-uniform; skipped for all-false masks)
        const int qq = q0 + s * 16 + t;
        for (int kvt = 0; kvt < 4; ++kvt)
          for (int r = 0; r < 4; ++r) {
            const int kv = kv0 + kvt * 16 + (g << 2) + r;
            if ((f1 && kp[(size_t)b * 2048 + kv]) || (f0 && am[(size_t)qq * 2048 + kv])) sT[kvt][r] = -1e9f;
          }
      }
      // online softmax for q = q0 + s*16 + t (column reduce over the 4 g-lanes)
      f32x4 m4 = vmax4(vmax4(sT[0], sT[1]), vmax4(sT[2], sT[3]));
      float tm = fmaxf(fmaxf(m4[0], m4[1]), fmaxf(m4[2], m4[3]));
      tm = fmaxf(tm, __shfl_xor(tm, 16));
      tm = fmaxf(tm, __shfl_xor(tm, 32));
      const float nm = fmaxf(mx[s], tm);
      const float al = __expf(mx[s] - nm);
      mx[s] = nm;
      f32x4 ps4 = (f32x4){0.f, 0.f, 0.f, 0.f};
#pragma unroll
      for (int kvt = 0; kvt < 4; ++kvt) {
        f32x4 p;
#pragma unroll
        for (int r = 0; r < 4; ++r) p[r] = __expf(sT[kvt][r] - nm);
        ps4 += p;
        u32x2 pw;
        pw[0] = __builtin_bit_cast(u32, __builtin_amdgcn_cvt_pkrtz(p[0], p[1]));
        pw[1] = __builtin_bit_cast(u32, __builtin_amdgcn_cvt_pkrtz(p[2], p[3]));
        // row t, f16-cols kvt*16+4g..+3; byte = t*128 + kvt*32 + g*8, XOR-swizzled
        *reinterpret_cast<u32x2*>(PBs + ((t * 128 + kvt * 32 + g * 8) ^ swz)) = pw;
      }
      lsum[s] = lsum[s] * al + (ps4[0] + ps4[1] + ps4[2] + ps4[3]);
      // B-frag read: lane (t,g) gets P[q=t][kv=kk*32+g*8 .. +8]
#pragma unroll
      for (int kk = 0; kk < 2; ++kk)
        pb[s][kk] = *reinterpret_cast<const f16x8*>(PBs + ((t * 128 + kk * 64 + g * 16) ^ swz));
#pragma unroll
      for (int dkt = 0; dkt < 4; ++dkt) o[s][dkt] *= al;
    }
    // PV: O^T[dk][q] += V^T x P^T
    __builtin_amdgcn_s_setprio(1);
#pragma unroll
    for (int s = 0; s < 2; ++s)
#pragma unroll
      for (int dkt = 0; dkt < 4; ++dkt) {
        o[s][dkt] = MFMA16(av[dkt][0], pb[s][0], o[s][dkt]);
        o[s][dkt] = MFMA16(av[dkt][1], pb[s][1], o[s][dkt]);
      }
    __builtin_amdgcn_s_setprio(0);
  }
  // finalize: sum over the 4-lane column, normalize, store.
#pragma unroll
  for (int s = 0; s < 2; ++s) {
    float l = lsum[s];
    l += __shfl_xor(l, 16);
    l += __shfl_xor(l, 32);
    const float inv = 1.0f / l;
#pragma unroll
    for (int dkt = 0; dkt < 4; ++dkt) {
      f16x4 vv;
#pragma unroll
      for (int r = 0; r < 4; ++r) vv[r] = (f16)(o[s][dkt][r] * inv);
      *reinterpret_cast<f16x4*>(y + (rowQ + s * 16 + t) * 1024 + hc + dkt * 16 + (g << 2)) = vv;
    }
  }
}

// ---------------- launch ----------------
extern "C" void kernel_launch(void* const* d_in, const int* in_sizes, int n_in,
                              void* d_out, int out_size, void* d_ws, size_t ws_size,
                              hipStream_t stream) {
  const float* q = (const float*)d_in[0];
  const float* k = (const float*)d_in[1];
  const float* v = (const float*)d_in[2];
  const unsigned char* kpm = (const unsigned char*)d_in[3];
  const unsigned char* amask = (const unsigned char*)d_in[4];
  const float* Wq = (const float*)d_in[5];
  const float* bq = (const float*)d_in[6];
  const float* Wk = (const float*)d_in[7];
  const float* bk = (const float*)d_in[8];
  const float* Wv = (const float*)d_in[9];
  const float* bv = (const float*)d_in[10];
  const float* Wo = (const float*)d_in[11];
  const float* bo = (const float*)d_in[12];
  float* out = (float*)d_out;

  char* ws = (char*)d_ws;
  const size_t SZ = 16777216;  // one [8192,1024] f16 buffer
  f16* qb = (f16*)(ws + 0 * SZ);
  f16* kb = (f16*)(ws + 1 * SZ);
  f16* vb = (f16*)(ws + 2 * SZ);
  f16* qhp = (f16*)(ws + 3 * SZ);
  f16* khp = (f16*)(ws + 4 * SZ);
  f16* vhT = (f16*)(ws + 5 * SZ);  // [4096][2048] f16: (b*1024 + h*64 + dk) x kv
  f16* yb = (f16*)(ws + 6 * SZ);
  f16* wqb = (f16*)(ws + 7 * SZ + 0 * 2097152);
  f16* wkb = (f16*)(ws + 7 * SZ + 1 * 2097152);
  f16* wvb = (f16*)(ws + 7 * SZ + 2 * 2097152);
  f16* wob = (f16*)(ws + 7 * SZ + 3 * 2097152);
  int* flags = (int*)(ws + 7 * SZ + 4 * 2097152);

  cvt_all<<<28672, 256, 0, stream>>>(q, k, v, Wq, Wk, Wv, Wo, qb, kb, vb, wqb, wkb, wvb, wob, flags);
  mask_flags_kernel<<<1024, 256, 0, stream>>>(amask, kpm, flags);
  gemm_qkv<<<1536, 256, 0, stream>>>(qb, kb, vb, wqb, wkb, wvb, bq, bk, bv, qhp, khp, vhT);
  attn_kernel<<<1024, 256, 0, stream>>>(qhp, khp, vhT, amask, kpm, flags, yb);
  gemm_out<<<512, 256, 0, stream>>>(yb, wob, bo, out);
}

// Round 4
// 391.371 us; speedup vs baseline: 1.3506x; 1.2810x over previous
//
#include <hip/hip_runtime.h>

// ---------------------------------------------------------------------------
// MultiheadAttention  B=4 S=2048 D=1024 H=16 DK=64
// cvt -> merged QKV proj GEMM (m97-style global_load_lds, V writes V^T)
//     -> flash attention (8-wave block, LDS-staged K/V via swizzled-source
//        global_load_lds, swapped QK^T, P^T via per-wave swizzled LDS)
//     -> out GEMM.
// ---------------------------------------------------------------------------

typedef _Float16 f16;
typedef _Float16 f16x8 __attribute__((ext_vector_type(8)));
typedef _Float16 f16x4 __attribute__((ext_vector_type(4)));
typedef float f32x4 __attribute__((ext_vector_type(4)));
typedef unsigned int u32;
typedef unsigned int u32x2 __attribute__((ext_vector_type(2)));

#define MFMA16(a, b, c) __builtin_amdgcn_mfma_f32_16x16x32_f16((a), (b), (c), 0, 0, 0)

__device__ __forceinline__ f32x4 vmax4(f32x4 a, f32x4 b) {
  f32x4 r;
  r[0] = fmaxf(a[0], b[0]);
  r[1] = fmaxf(a[1], b[1]);
  r[2] = fmaxf(a[2], b[2]);
  r[3] = fmaxf(a[3], b[3]);
  return r;
}

// async global->LDS, 16B per lane; LDS dest = wave-uniform base + lane*16.
__device__ __forceinline__ void gload16(const f16* gp, char* lp) {
  __builtin_amdgcn_global_load_lds((__attribute__((address_space(1))) void*)(void*)gp,
                                   (__attribute__((address_space(3))) void*)lp, 16, 0, 0);
}

// bijective XCD swizzle (nblk % 8 == 0): same-XCD blocks get contiguous work.
__device__ __forceinline__ int xcd_swz(int bid, int nblk) {
  return (bid & 7) * (nblk >> 3) + (bid >> 3);
}

// ---------------- conversion kernels ----------------
// blocks [0,24576): q,k,v (8192 blocks each); [24576,28672): Wq,Wk,Wv,Wo (1024 each).
__global__ void cvt_all(const float* __restrict__ q, const float* __restrict__ k,
                        const float* __restrict__ v, const float* __restrict__ w0,
                        const float* __restrict__ w1, const float* __restrict__ w2,
                        const float* __restrict__ w3, f16* __restrict__ qo,
                        f16* __restrict__ ko, f16* __restrict__ vo, f16* __restrict__ o0,
                        f16* __restrict__ o1, f16* __restrict__ o2, f16* __restrict__ o3,
                        int* __restrict__ flags) {
  const int bid = blockIdx.x;
  if (bid == 0 && threadIdx.x < 2) flags[threadIdx.x] = 0;  // stream-ordered before mask_flags
  const float* src;
  f16* dst;
  long idx;
  if (bid < 24576) {
    const int a = bid >> 13;
    idx = (long)(((bid & 8191) << 8) + threadIdx.x) * 4;
    src = (a == 0) ? q : (a == 1) ? k : v;
    dst = (a == 0) ? qo : (a == 1) ? ko : vo;
  } else {
    const int wb = bid - 24576;
    const int a = wb >> 10;
    idx = (long)(((wb & 1023) << 8) + threadIdx.x) * 4;
    src = (a == 0) ? w0 : (a == 1) ? w1 : (a == 2) ? w2 : w3;
    dst = (a == 0) ? o0 : (a == 1) ? o1 : (a == 2) ? o2 : o3;
  }
  const float4 f = *reinterpret_cast<const float4*>(src + idx);
  f16x4 o;
  o[0] = (f16)f.x; o[1] = (f16)f.y; o[2] = (f16)f.z; o[3] = (f16)f.w;
  *reinterpret_cast<f16x4*>(dst + idx) = o;
}

__global__ void mask_flags_kernel(const unsigned char* __restrict__ am,
                                  const unsigned char* __restrict__ kp, int* __restrict__ flags) {
  const int tid = blockIdx.x * 256 + threadIdx.x;
  const uint4 u = reinterpret_cast<const uint4*>(am)[tid];
  if (u.x | u.y | u.z | u.w) atomicOr(flags, 1);
  if (tid < 512) {
    const uint4 w = reinterpret_cast<const uint4*>(kp)[tid];
    if (w.x | w.y | w.z | w.w) atomicOr(flags + 1, 1);
  }
}

// ---------------- GEMM core: C[M,1024] = A[M,1024] * B[1024,1024]^T + bias ----
// m97 structure: 128x128 tile, BK=64, global_load_lds(16B) -> LINEAR LDS,
// 2 barriers per K-step, 4 waves x (64x64 out), 16x16x32 MFMA.
__device__ __forceinline__ void stC(float* p, float v) { *p = v; }
__device__ __forceinline__ void stC(f16* p, float v) { *p = (f16)v; }

template <typename OutT>
__device__ __forceinline__ void gemm_core(const f16* __restrict__ A, const f16* __restrict__ B,
                                          const float* __restrict__ bias, OutT* __restrict__ C,
                                          int br, int bc, int transp) {
  __shared__ __align__(16) char As[16384];  // [128 rows][64 k] f16, linear
  __shared__ __align__(16) char Bs[16384];
  const int tid = threadIdx.x;
  const int w = tid >> 6, lane = tid & 63, t = lane & 15, g = lane >> 4;
  const int rowBase = br << 7, colBase = bc << 7;
  const int wr = w >> 1, wc = w & 1;
  const int lr = lane >> 3, lc = lane & 7;  // lane's (row, 16B-col) within an 8-row chunk

  f32x4 acc[4][4];
#pragma unroll
  for (int m = 0; m < 4; ++m)
#pragma unroll
    for (int n = 0; n < 4; ++n) acc[m][n] = (f32x4){0.f, 0.f, 0.f, 0.f};

  const f16* gA = A + (size_t)(rowBase + w * 32 + lr) * 1024 + lc * 8;
  const f16* gB = B + (size_t)(colBase + w * 32 + lr) * 1024 + lc * 8;
  char* lA = As + w * 32 * 128;
  char* lB = Bs + w * 32 * 128;

  for (int ks = 0; ks < 16; ++ks) {
    const int k0 = ks << 6;
#pragma unroll
    for (int c = 0; c < 4; ++c) {
      gload16(gA + (size_t)(c * 8) * 1024 + k0, lA + c * 1024);
      gload16(gB + (size_t)(c * 8) * 1024 + k0, lB + c * 1024);
    }
    __syncthreads();  // drains vmcnt: staged tile visible
#pragma unroll
    for (int kk = 0; kk < 2; ++kk) {
      f16x8 af[4], bf[4];
#pragma unroll
      for (int m = 0; m < 4; ++m)
        af[m] = *reinterpret_cast<const f16x8*>(As + ((wr << 6) + (m << 4) + t) * 128 + (kk << 6) + (g << 4));
#pragma unroll
      for (int n = 0; n < 4; ++n)
        bf[n] = *reinterpret_cast<const f16x8*>(Bs + ((wc << 6) + (n << 4) + t) * 128 + (kk << 6) + (g << 4));
#pragma unroll
      for (int m = 0; m < 4; ++m)
#pragma unroll
        for (int n = 0; n < 4; ++n) acc[m][n] = MFMA16(af[m], bf[n], acc[m][n]);
    }
    __syncthreads();  // readers done before next tile's gload_lds overwrites
  }
  // epilogue. D frag: col = lane&15, row = (lane>>4)*4 + r (m89-verified).
#pragma unroll
  for (int n = 0; n < 4; ++n) {
    const int col = colBase + (wc << 6) + (n << 4) + t;
    const float bv = bias[col];
#pragma unroll
    for (int m = 0; m < 4; ++m) {
      const int row0 = rowBase + (wr << 6) + (m << 4) + (g << 2);
      if (transp) {  // write C^T: [4096][2048] f16, idx = (b*1024 + col)*2048 + s
        const int bI = row0 >> 11, s0 = row0 & 2047;
        f16x4 vv;
#pragma unroll
        for (int r = 0; r < 4; ++r) vv[r] = (f16)(acc[m][n][r] + bv);
        *reinterpret_cast<f16x4*>((f16*)C + ((size_t)(bI << 10) + col) * 2048 + s0) = vv;
      } else {
#pragma unroll
        for (int r = 0; r < 4; ++r) stC(C + (size_t)(row0 + r) * 1024 + col, acc[m][n][r] + bv);
      }
    }
  }
}

// merged Q/K/V projections: 1536 blocks (512 per GEMM), XCD-swizzled.
__global__ __launch_bounds__(256) void gemm_qkv(const f16* __restrict__ qb, const f16* __restrict__ kb,
                                                const f16* __restrict__ vb, const f16* __restrict__ wq,
                                                const f16* __restrict__ wk, const f16* __restrict__ wv,
                                                const float* __restrict__ bq, const float* __restrict__ bk,
                                                const float* __restrict__ bv, f16* __restrict__ qo,
                                                f16* __restrict__ ko, f16* __restrict__ vT) {
  const int lid = xcd_swz(blockIdx.x, 1536);
  const int bz = lid >> 9, rem = lid & 511;
  const int br = rem >> 3, bc = rem & 7;
  const f16* A = (bz == 0) ? qb : (bz == 1) ? kb : vb;
  const f16* Bm = (bz == 0) ? wq : (bz == 1) ? wk : wv;
  const float* bias = (bz == 0) ? bq : (bz == 1) ? bk : bv;
  f16* C = (bz == 0) ? qo : (bz == 1) ? ko : vT;
  gemm_core<f16>(A, Bm, bias, C, br, bc, bz == 2);
}

__global__ __launch_bounds__(256) void gemm_out(const f16* __restrict__ A, const f16* __restrict__ Bm,
                                                const float* __restrict__ bias, float* __restrict__ C) {
  const int lid = xcd_swz(blockIdx.x, 512);
  gemm_core<float>(A, Bm, bias, C, lid >> 3, lid & 7, 0);
}

// ---------------- flash attention ----------------
// 8 waves/block (512 thr), QBLK=128 (16 q-rows per wave), KVBLK=64.
// K,V tiles staged ONCE per block into LDS via global_load_lds with
// XOR-preswizzled per-lane GLOBAL source (linear LDS dest, rule #21),
// shared by all 8 waves. ds_read_b128 fragments use the matching XOR.
// S^T = mfma(K, Q): lane (t,g) holds S^T[kv=kv0+kvt*16+4g+r][q=q0+t].
// P^T round-trips a per-wave XOR-swizzled LDS tile (no cross-wave sync).
// PV: O^T = mfma(V^T, P^T).
__global__ __launch_bounds__(512) void attn_kernel(const f16* __restrict__ qh, const f16* __restrict__ kh,
                                                   const f16* __restrict__ vT,
                                                   const unsigned char* __restrict__ am,
                                                   const unsigned char* __restrict__ kp,
                                                   const int* __restrict__ flags, f16* __restrict__ y) {
  __shared__ __align__(16) char KT[8192];   // [64 kv][128B dk], source-swizzled
  __shared__ __align__(16) char VVT[8192];  // [64 dk][128B kv], source-swizzled
  __shared__ __align__(16) char PB[16384];  // 8 waves x [16 q][128B kv]
  const int tid = threadIdx.x;
  const int w = tid >> 6, lane = tid & 63, t = lane & 15, g = lane >> 4;
  const int lid = xcd_swz(blockIdx.x, 1024);  // each head's q-tiles share an XCD L2
  const int qt = lid & 15, bh = lid >> 4;
  const int h = bh & 15, b = bh >> 4;
  const int hc = h << 6;
  const int q0 = qt * 128 + w * 16;
  const size_t rowQ = (size_t)b * 2048 + q0;
  const size_t kBase = (size_t)b * 2048 * 1024 + hc;  // + kv*1024
  const size_t vBase = (size_t)bh * 64 * 2048;        // + dk*2048 + kv
  char* PBw = PB + (w << 11);
  const int swz = (t & 7) << 4;

  // staging geometry: thread covers chunk li = tid (row = li>>3, 16B col = li&7)
  const int srow = tid >> 3;
  const int scolb = (tid & 7) << 4;
  const int sswz = scolb ^ ((srow & 7) << 4);
  const f16* gK = kh + kBase + (size_t)srow * 1024 + (sswz >> 1);
  const f16* gV = vT + vBase + (size_t)srow * 2048 + (sswz >> 1);
  char* lK = KT + tid * 16;
  char* lV = VVT + tid * 16;

  // Q B-fragment (1 strip), scale 1/8 folded in (exact in f16).
  f16x8 bq[2];
#pragma unroll
  for (int h2 = 0; h2 < 2; ++h2) {
    f16x8 qv = *reinterpret_cast<const f16x8*>(qh + (rowQ + t) * 1024 + hc + h2 * 32 + g * 8);
#pragma unroll
    for (int j = 0; j < 8; ++j) qv[j] = qv[j] * (f16)0.125f;
    bq[h2] = qv;
  }

  f32x4 o[4];
#pragma unroll
  for (int d = 0; d < 4; ++d) o[d] = (f32x4){0.f, 0.f, 0.f, 0.f};
  float mx = -3.0e38f, lsum = 0.f;
  const int f0 = flags[0], f1 = flags[1];

  for (int tk = 0; tk < 32; ++tk) {
    const int kv0 = tk << 6;
    // stage K and V tiles (1 chunk each per thread, async direct-to-LDS)
    gload16(gK + (size_t)kv0 * 1024, lK);
    gload16(gV + kv0, lV);
    __syncthreads();  // drains vmcnt: tiles visible

    // K fragments from LDS
    f16x8 ak[4][2];
#pragma unroll
    for (int kvt = 0; kvt < 4; ++kvt)
#pragma unroll
      for (int h2 = 0; h2 < 2; ++h2)
        ak[kvt][h2] = *reinterpret_cast<const f16x8*>(KT + (kvt * 16 + t) * 128 + ((h2 * 64 + g * 16) ^ swz));

    // QK^T (swapped)
    f32x4 sT[4];
    __builtin_amdgcn_s_setprio(1);
#pragma unroll
    for (int kvt = 0; kvt < 4; ++kvt) {
      f32x4 z = (f32x4){0.f, 0.f, 0.f, 0.f};
      z = MFMA16(ak[kvt][0], bq[0], z);
      z = MFMA16(ak[kvt][1], bq[1], z);
      sT[kvt] = z;
    }
    __builtin_amdgcn_s_setprio(0);
    if (f0 | f1) {  // mask slow path (wave-uniform; skipped for all-false masks)
      const int qq = q0 + t;
      for (int kvt = 0; kvt < 4; ++kvt)
        for (int r = 0; r < 4; ++r) {
          const int kv = kv0 + kvt * 16 + (g << 2) + r;
          if ((f1 && kp[(size_t)b * 2048 + kv]) || (f0 && am[(size_t)qq * 2048 + kv])) sT[kvt][r] = -1e9f;
        }
    }
    // online softmax for q = q0 + t (column reduce over the 4 g-lanes)
    f32x4 m4 = vmax4(vmax4(sT[0], sT[1]), vmax4(sT[2], sT[3]));
    float tm = fmaxf(fmaxf(m4[0], m4[1]), fmaxf(m4[2], m4[3]));
    tm = fmaxf(tm, __shfl_xor(tm, 16));
    tm = fmaxf(tm, __shfl_xor(tm, 32));
    const float nm = fmaxf(mx, tm);
    const float al = __expf(mx - nm);
    mx = nm;
    f32x4 ps4 = (f32x4){0.f, 0.f, 0.f, 0.f};
#pragma unroll
    for (int kvt = 0; kvt < 4; ++kvt) {
      f32x4 p;
#pragma unroll
      for (int r = 0; r < 4; ++r) p[r] = __expf(sT[kvt][r] - nm);
      ps4 += p;
      u32x2 pw;
      pw[0] = __builtin_bit_cast(u32, __builtin_amdgcn_cvt_pkrtz(p[0], p[1]));
      pw[1] = __builtin_bit_cast(u32, __builtin_amdgcn_cvt_pkrtz(p[2], p[3]));
      // row t, f16-cols kvt*16+4g..+3; byte = t*128 + kvt*32 + g*8, XOR-swizzled
      *reinterpret_cast<u32x2*>(PBw + ((t * 128 + kvt * 32 + g * 8) ^ swz)) = pw;
    }
    lsum = lsum * al + (ps4[0] + ps4[1] + ps4[2] + ps4[3]);
    // B-frag read: lane (t,g) gets P[q=t][kv=kk*32+g*8 .. +8]
    f16x8 pb[2];
#pragma unroll
    for (int kk = 0; kk < 2; ++kk)
      pb[kk] = *reinterpret_cast<const f16x8*>(PBw + ((t * 128 + kk * 64 + g * 16) ^ swz));
#pragma unroll
    for (int d = 0; d < 4; ++d) o[d] *= al;

    // V^T fragments + PV: O^T[dk][q] += V^T x P^T
    f16x8 av[4][2];
#pragma unroll
    for (int dkt = 0; dkt < 4; ++dkt)
#pragma unroll
      for (int kk = 0; kk < 2; ++kk)
        av[dkt][kk] = *reinterpret_cast<const f16x8*>(VVT + (dkt * 16 + t) * 128 + ((kk * 64 + g * 16) ^ swz));
    __builtin_amdgcn_s_setprio(1);
#pragma unroll
    for (int dkt = 0; dkt < 4; ++dkt) {
      o[dkt] = MFMA16(av[dkt][0], pb[0], o[dkt]);
      o[dkt] = MFMA16(av[dkt][1], pb[1], o[dkt]);
    }
    __builtin_amdgcn_s_setprio(0);
    __syncthreads();  // all readers done before next tile's staging overwrites
  }
  // finalize: sum over the 4-lane column, normalize, store.
  float l = lsum;
  l += __shfl_xor(l, 16);
  l += __shfl_xor(l, 32);
  const float inv = 1.0f / l;
#pragma unroll
  for (int dkt = 0; dkt < 4; ++dkt) {
    f16x4 vv;
#pragma unroll
    for (int r = 0; r < 4; ++r) vv[r] = (f16)(o[dkt][r] * inv);
    *reinterpret_cast<f16x4*>(y + (rowQ + t) * 1024 + hc + dkt * 16 + (g << 2)) = vv;
  }
}

// ---------------- launch ----------------
extern "C" void kernel_launch(void* const* d_in, const int* in_sizes, int n_in,
                              void* d_out, int out_size, void* d_ws, size_t ws_size,
                              hipStream_t stream) {
  const float* q = (const float*)d_in[0];
  const float* k = (const float*)d_in[1];
  const float* v = (const float*)d_in[2];
  const unsigned char* kpm = (const unsigned char*)d_in[3];
  const unsigned char* amask = (const unsigned char*)d_in[4];
  const float* Wq = (const float*)d_in[5];
  const float* bq = (const float*)d_in[6];
  const float* Wk = (const float*)d_in[7];
  const float* bk = (const float*)d_in[8];
  const float* Wv = (const float*)d_in[9];
  const float* bv = (const float*)d_in[10];
  const float* Wo = (const float*)d_in[11];
  const float* bo = (const float*)d_in[12];
  float* out = (float*)d_out;

  char* ws = (char*)d_ws;
  const size_t SZ = 16777216;  // one [8192,1024] f16 buffer
  f16* qb = (f16*)(ws + 0 * SZ);
  f16* kb = (f16*)(ws + 1 * SZ);
  f16* vb = (f16*)(ws + 2 * SZ);
  f16* qhp = (f16*)(ws + 3 * SZ);
  f16* khp = (f16*)(ws + 4 * SZ);
  f16* vhT = (f16*)(ws + 5 * SZ);  // [4096][2048] f16: (b*1024 + h*64 + dk) x kv
  f16* yb = (f16*)(ws + 6 * SZ);
  f16* wqb = (f16*)(ws + 7 * SZ + 0 * 2097152);
  f16* wkb = (f16*)(ws + 7 * SZ + 1 * 2097152);
  f16* wvb = (f16*)(ws + 7 * SZ + 2 * 2097152);
  f16* wob = (f16*)(ws + 7 * SZ + 3 * 2097152);
  int* flags = (int*)(ws + 7 * SZ + 4 * 2097152);

  cvt_all<<<28672, 256, 0, stream>>>(q, k, v, Wq, Wk, Wv, Wo, qb, kb, vb, wqb, wkb, wvb, wob, flags);
  mask_flags_kernel<<<1024, 256, 0, stream>>>(amask, kpm, flags);
  gemm_qkv<<<1536, 256, 0, stream>>>(qb, kb, vb, wqb, wkb, wvb, bq, bk, bv, qhp, khp, vhT);
  attn_kernel<<<1024, 512, 0, stream>>>(qhp, khp, vhT, amask, kpm, flags, yb);
  gemm_out<<<512, 256, 0, stream>>>(yb, wob, bo, out);
}